// Round 6
// baseline (868.692 us; speedup 1.0000x reference)
//
#include <hip/hip_runtime.h>
#include <hip/hip_bf16.h>

#define E_ 8
#define D_ 1024
#define F_ 4096
#define S_ 2048
#define B_ 2
#define T_ 4096
#define CAP 1024
#define LN_EPS 1e-5f
#define NTABF 2048

typedef __attribute__((ext_vector_type(8))) short short8;
typedef __attribute__((ext_vector_type(4))) float f32x4;

__device__ __forceinline__ unsigned short f2bf(float f) {
  __hip_bfloat16 h = __float2bfloat16(f);
  return *reinterpret_cast<unsigned short*>(&h);
}

// ---------- fused gating + LN + bucket scatter + out init (x + b2[e]) ----------
__global__ __launch_bounds__(256) void gate_ln_kernel(
    const float* __restrict__ x, const float* __restrict__ cent,
    const float* __restrict__ g_, const float* __restrict__ bb_,
    const float* __restrict__ b2_,
    int* __restrict__ counts, int* __restrict__ perm,
    unsigned short* __restrict__ Xb, float* __restrict__ outp) {
  int token = blockIdx.x * 4 + (threadIdx.x >> 6);
  int lane = threadIdx.x & 63;
  int s = token & (S_ - 1), b = token >> 11;
  const float* xr = x + ((size_t)s * B_ + b) * D_;
  float* orow = outp + ((size_t)s * B_ + b) * D_;

  float v[16];
  float acc[E_];
#pragma unroll
  for (int e = 0; e < E_; ++e) acc[e] = 0.f;
  float sum = 0.f, sq = 0.f;
#pragma unroll
  for (int c = 0; c < 4; ++c) {
    f32x4 xv = *(const f32x4*)(xr + c * 256 + lane * 4);
    v[c * 4 + 0] = xv.x; v[c * 4 + 1] = xv.y; v[c * 4 + 2] = xv.z; v[c * 4 + 3] = xv.w;
    sum += xv.x + xv.y + xv.z + xv.w;
    sq += xv.x * xv.x + xv.y * xv.y + xv.z * xv.z + xv.w * xv.w;
#pragma unroll
    for (int e = 0; e < E_; ++e) {
      f32x4 cv = *(const f32x4*)(cent + e * D_ + c * 256 + lane * 4);
      acc[e] += xv.x * cv.x + xv.y * cv.y + xv.z * cv.z + xv.w * cv.w;
    }
  }
#pragma unroll
  for (int off = 32; off > 0; off >>= 1) {
    sum += __shfl_down(sum, off);
    sq += __shfl_down(sq, off);
#pragma unroll
    for (int e = 0; e < E_; ++e) acc[e] += __shfl_down(acc[e], off);
  }
  int best = 0, slot = 0;
  if (lane == 0) {
    float bv = acc[0];
#pragma unroll
    for (int e = 1; e < E_; ++e) if (acc[e] > bv) { bv = acc[e]; best = e; }
    slot = atomicAdd(&counts[best], 1);
    perm[best * CAP + slot] = token;
  }
  best = __shfl(best, 0); slot = __shfl(slot, 0);
  sum = __shfl(sum, 0); sq = __shfl(sq, 0);
  float mu = sum * (1.f / D_);
  float var = sq * (1.f / D_) - mu * mu;
  float rstd = rsqrtf(var + LN_EPS);
  int e = best;
  unsigned short* dst = Xb + (size_t)(e * CAP + slot) * D_;
#pragma unroll
  for (int c = 0; c < 4; ++c) {
    int d = c * 256 + lane * 4;
    f32x4 gv = *(const f32x4*)(g_ + e * D_ + d);
    f32x4 bv = *(const f32x4*)(bb_ + e * D_ + d);
    f32x4 b2v = *(const f32x4*)(b2_ + e * D_ + d);
    ushort4 o;
    o.x = f2bf((v[c * 4 + 0] - mu) * rstd * gv.x + bv.x);
    o.y = f2bf((v[c * 4 + 1] - mu) * rstd * gv.y + bv.y);
    o.z = f2bf((v[c * 4 + 2] - mu) * rstd * gv.z + bv.z);
    o.w = f2bf((v[c * 4 + 3] - mu) * rstd * gv.w + bv.w);
    *(ushort4*)(dst + d) = o;
    f32x4 oi;
    oi.x = v[c * 4 + 0] + b2v.x; oi.y = v[c * 4 + 1] + b2v.y;
    oi.z = v[c * 4 + 2] + b2v.z; oi.w = v[c * 4 + 3] + b2v.w;
    *(f32x4*)(orow + d) = oi;
  }
}

// ---------- prefix + XCD-grouped flat schedule tables ----------
// entry: (e<<24)|(m<<16)|(n<<8)|kz ; -1 empty. Table idx i -> XCD i&7; all
// m-blocks of a (e,n[,kz]) group land on one XCD at adjacent positions.
__global__ __launch_bounds__(256) void prefix_kernel(
    const int* __restrict__ counts, int* __restrict__ offs,
    int* __restrict__ tabF1, int* __restrict__ tabF2) {
  __shared__ int q[8][256];
  __shared__ int ql[8];
  __shared__ int nb[E_];
  const int tid = threadIdx.x;
  if (tid == 0) {
    int s = 0;
    for (int e = 0; e < E_; ++e) {
      offs[e] = s;
      nb[e] = (counts[e] + 127) >> 7;
      s += counts[e];
    }
    offs[E_] = s;
    for (int x = 0; x < 8; ++x) ql[x] = 0;
    int g = 0;
    for (int n = 0; n < F_ / 128; ++n)
      for (int e = 0; e < E_; ++e) {
        int x = g & 7; ++g;
        for (int m = 0; m < nb[e]; ++m) q[x][ql[x]++] = (e << 24) | (m << 16) | (n << 8);
      }
  }
  __syncthreads();
  for (int i = tid; i < NTABF; i += 256) {
    int p = i >> 3, x = i & 7;
    tabF1[i] = (p < ql[x]) ? q[x][p] : -1;
  }
  __syncthreads();
  if (tid == 0) {
    for (int x = 0; x < 8; ++x) ql[x] = 0;
    int g = 0;
    for (int kz = 0; kz < 4; ++kz)
      for (int n = 0; n < D_ / 128; ++n)
        for (int e = 0; e < E_; ++e) {
          int x = g & 7; ++g;
          for (int m = 0; m < nb[e]; ++m)
            q[x][ql[x]++] = (e << 24) | (m << 16) | (n << 8) | kz;
        }
  }
  __syncthreads();
  for (int i = tid; i < NTABF; i += 256) {
    int p = i >> 3, x = i & 7;
    tabF2[i] = (p < ql[x]) ? q[x][p] : -1;
  }
}

// ---------- grouped GEMM, 128x128 tile, distance-2 pipeline, cvt-at-write ----------
// A[rows][K] bf16, W[E][K][N] fp32.
// MODE 0: H = relu(A*W1 + b1) -> bf16 compact   MODE 1: atomicAdd into out (split-K)
template <int K, int N, int MODE, int KSPLIT>
__global__ __launch_bounds__(256, 4) void moe_gemm_kernel(
    const unsigned short* __restrict__ A,
    const float* __restrict__ W,
    const float* __restrict__ bias,
    const int* __restrict__ counts,
    const int* __restrict__ offs,
    const int* __restrict__ tab,
    const int* __restrict__ perm,
    void* __restrict__ outp) {
  const int te = tab[blockIdx.x];
  if (te < 0) return;
  const int e = te >> 24;
  const int m0 = ((te >> 16) & 255) << 7;
  const int n0 = ((te >> 8) & 255) << 7;
  const int kz = te & 255;
  const int cnt = counts[e];
  const int aoff = (MODE == 0) ? e * CAP : offs[e];
  const int hoff = offs[e];
  const int kstart = kz * (K / KSPLIT);
  constexpr int NSTEP = (K / KSPLIT) / 32;
  static_assert(NSTEP >= 4 && (NSTEP % 2) == 0, "NSTEP must be even >= 4");

  const int tid = threadIdx.x;
  const int lane = tid & 63;
  const int wave = tid >> 6;

  // per buffer: [q 0..3][row/col 0..127][8 bf16]
  __shared__ __align__(16) unsigned short lA[2][4096];
  __shared__ __align__(16) unsigned short lB[2][4096];

  // A: thread covers cells (qa, ra) and (qa+2, ra)
  const int ra = tid & 127;
  const int qa = tid >> 7;  // 0..1
  const int arow = aoff + min(m0 + ra, cnt - 1);
  const unsigned short* asrc = A + (size_t)arow * K + kstart + qa * 8;

  // B: wave q handles k-rows q*8..q*8+7; lane covers cols {lane, lane+64}
  const float* wsrc = W + (size_t)e * K * N + (size_t)(kstart + wave * 8) * N + n0 + lane;

  f32x4 acc[4][4] = {};
  const int wr = (wave >> 1) * 64;
  const int wc = (wave & 1) * 64;
  const int fr = lane & 15;
  const int fq = lane >> 4;

  // two named register slots (tile parity): slot s holds tile t with t&1==s
  short8 pA00, pA01, pA10, pA11;
  float pBa0[8], pBb0[8], pBa1[8], pBb1[8];

  // ---- prologue: load tile0 -> slot0, tile1 -> slot1; write slot0 -> buf0 ----
  pA00 = *(const short8*)(asrc);
  pA01 = *(const short8*)(asrc + 16);
#pragma unroll
  for (int j = 0; j < 8; ++j) {
    pBa0[j] = wsrc[(size_t)j * N];
    pBb0[j] = wsrc[(size_t)j * N + 64];
  }
  pA10 = *(const short8*)(asrc + 32);
  pA11 = *(const short8*)(asrc + 48);
  {
    const float* wp_ = wsrc + (size_t)32 * N;
#pragma unroll
    for (int j = 0; j < 8; ++j) {
      pBa1[j] = wp_[(size_t)j * N];
      pBb1[j] = wp_[(size_t)j * N + 64];
    }
  }
  *(short8*)&lA[0][qa * 1024 + ra * 8] = pA00;
  *(short8*)&lA[0][(qa + 2) * 1024 + ra * 8] = pA01;
  {
    short8 c0_, c1_;
#pragma unroll
    for (int j = 0; j < 8; ++j) {
      c0_[j] = (short)f2bf(pBa0[j]);
      c1_[j] = (short)f2bf(pBb0[j]);
    }
    *(short8*)&lB[0][wave * 1024 + lane * 8] = c0_;
    *(short8*)&lB[0][wave * 1024 + (lane + 64) * 8] = c1_;
  }
  asm volatile("s_waitcnt lgkmcnt(0)" ::: "memory");
  __builtin_amdgcn_s_barrier();
  asm volatile("" ::: "memory");

#define STEP_BODY(TV, CUR, NXT)                                                     \
  {                                                                                 \
    const int tv_ = (TV);                                                           \
    if (tv_ + 2 < NSTEP) { /* load tile tv+2 into slot CUR (raw, no cvt) */         \
      const unsigned short* ap_ = asrc + (tv_ + 2) * 32;                            \
      pA##CUR##0 = *(const short8*)ap_;                                             \
      pA##CUR##1 = *(const short8*)(ap_ + 16);                                      \
      const float* wp_ = wsrc + (size_t)(tv_ + 2) * 32 * N;                         \
      _Pragma("unroll") for (int j = 0; j < 8; ++j) {                               \
        pBa##CUR[j] = wp_[(size_t)j * N];                                           \
        pBb##CUR[j] = wp_[(size_t)j * N + 64];                                      \
      }                                                                             \
    }                                                                               \
    if (tv_ + 1 < NSTEP) { /* write slot NXT (tile tv+1, loaded last step) */       \
      *(short8*)&lA[NXT][qa * 1024 + ra * 8] = pA##NXT##0;                          \
      *(short8*)&lA[NXT][(qa + 2) * 1024 + ra * 8] = pA##NXT##1;                    \
      short8 c0_, c1_;                                                              \
      _Pragma("unroll") for (int j = 0; j < 8; ++j) {                               \
        c0_[j] = (short)f2bf(pBa##NXT[j]);                                          \
        c1_[j] = (short)f2bf(pBb##NXT[j]);                                          \
      }                                                                             \
      *(short8*)&lB[NXT][wave * 1024 + lane * 8] = c0_;                             \
      *(short8*)&lB[NXT][wave * 1024 + (lane + 64) * 8] = c1_;                      \
    }                                                                               \
    short8 af_[4], bf_[4];                                                          \
    _Pragma("unroll") for (int m = 0; m < 4; ++m)                                   \
        af_[m] = *(const short8*)&lA[CUR][fq * 1024 + (wr + m * 16 + fr) * 8];      \
    _Pragma("unroll") for (int n = 0; n < 4; ++n)                                   \
        bf_[n] = *(const short8*)&lB[CUR][fq * 1024 + (wc + n * 16 + fr) * 8];      \
    __builtin_amdgcn_s_setprio(1);                                                  \
    _Pragma("unroll") for (int m = 0; m < 4; ++m)                                   \
        _Pragma("unroll") for (int n = 0; n < 4; ++n)                               \
            acc[m][n] =                                                             \
                __builtin_amdgcn_mfma_f32_16x16x32_bf16(af_[m], bf_[n],             \
                                                        acc[m][n], 0, 0, 0);        \
    __builtin_amdgcn_s_setprio(0);                                                  \
    asm volatile("s_waitcnt lgkmcnt(0)" ::: "memory");                              \
    __builtin_amdgcn_s_barrier();                                                   \
    asm volatile("" ::: "memory");                                                  \
  }

  for (int t = 0; t < NSTEP; t += 2) {
    STEP_BODY(t, 0, 1);
    STEP_BODY(t + 1, 1, 0);
  }
#undef STEP_BODY

  if (MODE == 0) {
    unsigned short* Hout = (unsigned short*)outp;
    float bv[4];
#pragma unroll
    for (int n = 0; n < 4; ++n) bv[n] = bias[e * N + n0 + wc + n * 16 + fr];
#pragma unroll
    for (int m = 0; m < 4; ++m) {
#pragma unroll
      for (int j = 0; j < 4; ++j) {
        int rg = m0 + wr + m * 16 + fq * 4 + j;
        if (rg < cnt) {
          size_t base = (size_t)(hoff + rg) * N;
#pragma unroll
          for (int n = 0; n < 4; ++n) {
            float hv = acc[m][n][j] + bv[n];
            hv = fmaxf(hv, 0.f);
            Hout[base + n0 + wc + n * 16 + fr] = f2bf(hv);
          }
        }
      }
    }
  } else {
    float* Out = (float*)outp;
#pragma unroll
    for (int m = 0; m < 4; ++m) {
#pragma unroll
      for (int j = 0; j < 4; ++j) {
        int rg = m0 + wr + m * 16 + fq * 4 + j;
        if (rg < cnt) {
          int token = perm[e * CAP + rg];
          size_t base = ((size_t)(token & (S_ - 1)) * B_ + (token >> 11)) * (size_t)D_;
#pragma unroll
          for (int n = 0; n < 4; ++n)
            atomicAdd(&Out[base + n0 + wc + n * 16 + fr], acc[m][n][j]);
        }
      }
    }
  }
}

extern "C" void kernel_launch(void* const* d_in, const int* in_sizes, int n_in,
                              void* d_out, int out_size, void* d_ws, size_t ws_size,
                              hipStream_t stream) {
  const float* x    = (const float*)d_in[0];
  const float* cent = (const float*)d_in[1];
  const float* lng  = (const float*)d_in[2];
  const float* lnb  = (const float*)d_in[3];
  const float* W1   = (const float*)d_in[4];
  const float* b1   = (const float*)d_in[5];
  const float* W2   = (const float*)d_in[6];
  const float* b2   = (const float*)d_in[7];
  float* out = (float*)d_out;

  char* ws = (char*)d_ws;
  int* counts = (int*)(ws + 0);          // 8 ints
  int* offs   = (int*)(ws + 64);         // 9 ints
  int* tabF1  = (int*)(ws + 4096);       // NTABF ints (8KB)
  int* tabF2  = (int*)(ws + 12288);      // NTABF ints (8KB)
  int* perm   = (int*)(ws + 20480);      // [E][CAP] ints, 32KB
  unsigned short* Xb = (unsigned short*)(ws + ((size_t)1 << 18)); // [E][CAP][D] bf16, 16MB
  unsigned short* H  = (unsigned short*)(ws + ((size_t)1 << 25)); // [T][F] bf16 compact, 32MB

  if (ws_size < ((size_t)1 << 26)) return;  // need 64MB scratch

  hipMemsetAsync(counts, 0, 64, stream);
  gate_ln_kernel<<<T_ / 4, 256, 0, stream>>>(x, cent, lng, lnb, b2, counts, perm, Xb, out);
  prefix_kernel<<<1, 256, 0, stream>>>(counts, offs, tabF1, tabF2);
  // FF1: H = relu(Xb * W1 + b1)
  moe_gemm_kernel<D_, F_, 0, 1><<<NTABF, 256, 0, stream>>>(
      Xb, W1, b1, counts, offs, tabF1, perm, (void*)H);
  // FF2: out += H * W2 (split-K=4; out pre-initialized with x + b2)
  moe_gemm_kernel<F_, D_, 1, 4><<<NTABF, 256, 0, stream>>>(
      H, W2, nullptr, counts, offs, tabF2, perm, (void*)out);
}

// Round 7
// 361.080 us; speedup vs baseline: 2.4058x; 2.4058x over previous
//
#include <hip/hip_runtime.h>
#include <hip/hip_bf16.h>

#define E_ 8
#define D_ 1024
#define F_ 4096
#define S_ 2048
#define B_ 2
#define T_ 4096
#define CAP 1024
#define LN_EPS 1e-5f
#define NTABF 2048

typedef __attribute__((ext_vector_type(8))) short short8;
typedef __attribute__((ext_vector_type(4))) float f32x4;

__device__ __forceinline__ unsigned short f2bf(float f) {
  __hip_bfloat16 h = __float2bfloat16(f);
  return *reinterpret_cast<unsigned short*>(&h);
}

// ---------- fused gating + LN + bucket scatter + out init (x + b2[e]) ----------
__global__ __launch_bounds__(256) void gate_ln_kernel(
    const float* __restrict__ x, const float* __restrict__ cent,
    const float* __restrict__ g_, const float* __restrict__ bb_,
    const float* __restrict__ b2_,
    int* __restrict__ counts, int* __restrict__ perm,
    unsigned short* __restrict__ Xb, float* __restrict__ outp) {
  int token = blockIdx.x * 4 + (threadIdx.x >> 6);
  int lane = threadIdx.x & 63;
  int s = token & (S_ - 1), b = token >> 11;
  const float* xr = x + ((size_t)s * B_ + b) * D_;
  float* orow = outp + ((size_t)s * B_ + b) * D_;

  float v[16];
  float acc[E_];
#pragma unroll
  for (int e = 0; e < E_; ++e) acc[e] = 0.f;
  float sum = 0.f, sq = 0.f;
#pragma unroll
  for (int c = 0; c < 4; ++c) {
    f32x4 xv = *(const f32x4*)(xr + c * 256 + lane * 4);
    v[c * 4 + 0] = xv.x; v[c * 4 + 1] = xv.y; v[c * 4 + 2] = xv.z; v[c * 4 + 3] = xv.w;
    sum += xv.x + xv.y + xv.z + xv.w;
    sq += xv.x * xv.x + xv.y * xv.y + xv.z * xv.z + xv.w * xv.w;
#pragma unroll
    for (int e = 0; e < E_; ++e) {
      f32x4 cv = *(const f32x4*)(cent + e * D_ + c * 256 + lane * 4);
      acc[e] += xv.x * cv.x + xv.y * cv.y + xv.z * cv.z + xv.w * cv.w;
    }
  }
#pragma unroll
  for (int off = 32; off > 0; off >>= 1) {
    sum += __shfl_down(sum, off);
    sq += __shfl_down(sq, off);
#pragma unroll
    for (int e = 0; e < E_; ++e) acc[e] += __shfl_down(acc[e], off);
  }
  int best = 0, slot = 0;
  if (lane == 0) {
    float bv = acc[0];
#pragma unroll
    for (int e = 1; e < E_; ++e) if (acc[e] > bv) { bv = acc[e]; best = e; }
    slot = atomicAdd(&counts[best], 1);
    perm[best * CAP + slot] = token;
  }
  best = __shfl(best, 0); slot = __shfl(slot, 0);
  sum = __shfl(sum, 0); sq = __shfl(sq, 0);
  float mu = sum * (1.f / D_);
  float var = sq * (1.f / D_) - mu * mu;
  float rstd = rsqrtf(var + LN_EPS);
  int e = best;
  unsigned short* dst = Xb + (size_t)(e * CAP + slot) * D_;
#pragma unroll
  for (int c = 0; c < 4; ++c) {
    int d = c * 256 + lane * 4;
    f32x4 gv = *(const f32x4*)(g_ + e * D_ + d);
    f32x4 bv = *(const f32x4*)(bb_ + e * D_ + d);
    f32x4 b2v = *(const f32x4*)(b2_ + e * D_ + d);
    ushort4 o;
    o.x = f2bf((v[c * 4 + 0] - mu) * rstd * gv.x + bv.x);
    o.y = f2bf((v[c * 4 + 1] - mu) * rstd * gv.y + bv.y);
    o.z = f2bf((v[c * 4 + 2] - mu) * rstd * gv.z + bv.z);
    o.w = f2bf((v[c * 4 + 3] - mu) * rstd * gv.w + bv.w);
    *(ushort4*)(dst + d) = o;
    f32x4 oi;
    oi.x = v[c * 4 + 0] + b2v.x; oi.y = v[c * 4 + 1] + b2v.y;
    oi.z = v[c * 4 + 2] + b2v.z; oi.w = v[c * 4 + 3] + b2v.w;
    *(f32x4*)(orow + d) = oi;
  }
}

// ---------- prefix + XCD-grouped flat schedule tables ----------
// entry: (e<<24)|(m<<16)|(n<<8)|kz ; -1 empty. Table idx i -> XCD i&7; all
// m-blocks of a (e,n[,kz]) group land on one XCD at adjacent positions.
__global__ __launch_bounds__(256) void prefix_kernel(
    const int* __restrict__ counts, int* __restrict__ offs,
    int* __restrict__ tabF1, int* __restrict__ tabF2) {
  __shared__ int q[8][256];
  __shared__ int ql[8];
  __shared__ int nb[E_];
  const int tid = threadIdx.x;
  if (tid == 0) {
    int s = 0;
    for (int e = 0; e < E_; ++e) {
      offs[e] = s;
      nb[e] = (counts[e] + 127) >> 7;
      s += counts[e];
    }
    offs[E_] = s;
    for (int x = 0; x < 8; ++x) ql[x] = 0;
    int g = 0;
    for (int n = 0; n < F_ / 128; ++n)
      for (int e = 0; e < E_; ++e) {
        int x = g & 7; ++g;
        for (int m = 0; m < nb[e]; ++m) q[x][ql[x]++] = (e << 24) | (m << 16) | (n << 8);
      }
  }
  __syncthreads();
  for (int i = tid; i < NTABF; i += 256) {
    int p = i >> 3, x = i & 7;
    tabF1[i] = (p < ql[x]) ? q[x][p] : -1;
  }
  __syncthreads();
  if (tid == 0) {
    for (int x = 0; x < 8; ++x) ql[x] = 0;
    int g = 0;
    for (int kz = 0; kz < 4; ++kz)
      for (int n = 0; n < D_ / 128; ++n)
        for (int e = 0; e < E_; ++e) {
          int x = g & 7; ++g;
          for (int m = 0; m < nb[e]; ++m)
            q[x][ql[x]++] = (e << 24) | (m << 16) | (n << 8) | kz;
        }
  }
  __syncthreads();
  for (int i = tid; i < NTABF; i += 256) {
    int p = i >> 3, x = i & 7;
    tabF2[i] = (p < ql[x]) ? q[x][p] : -1;
  }
}

// ---------- grouped GEMM, 128x128 tile, distance-2 pipeline, cvt-at-write ----------
// A[rows][K] bf16, W[E][K][N] fp32.
// MODE 0: H = relu(A*W1 + b1) -> bf16 compact   MODE 1: atomicAdd into out (split-K)
// NOTE: __launch_bounds__(256,3): occupancy 4 (R6) forced VGPR 84->64 and
// spilled the pipeline registers to scratch -> 445MB writes, 3x slowdown.
template <int K, int N, int MODE, int KSPLIT>
__global__ __launch_bounds__(256, 3) void moe_gemm_kernel(
    const unsigned short* __restrict__ A,
    const float* __restrict__ W,
    const float* __restrict__ bias,
    const int* __restrict__ counts,
    const int* __restrict__ offs,
    const int* __restrict__ tab,
    const int* __restrict__ perm,
    void* __restrict__ outp) {
  const int te = tab[blockIdx.x];
  if (te < 0) return;
  const int e = te >> 24;
  const int m0 = ((te >> 16) & 255) << 7;
  const int n0 = ((te >> 8) & 255) << 7;
  const int kz = te & 255;
  const int cnt = counts[e];
  const int aoff = (MODE == 0) ? e * CAP : offs[e];
  const int hoff = offs[e];
  const int kstart = kz * (K / KSPLIT);
  constexpr int NSTEP = (K / KSPLIT) / 32;
  static_assert(NSTEP >= 4 && (NSTEP % 2) == 0, "NSTEP must be even >= 4");

  const int tid = threadIdx.x;
  const int lane = tid & 63;
  const int wave = tid >> 6;

  // per buffer: [q 0..3][row/col 0..127][8 bf16]
  __shared__ __align__(16) unsigned short lA[2][4096];
  __shared__ __align__(16) unsigned short lB[2][4096];

  // A: thread covers cells (qa, ra) and (qa+2, ra)
  const int ra = tid & 127;
  const int qa = tid >> 7;  // 0..1
  const int arow = aoff + min(m0 + ra, cnt - 1);
  const unsigned short* asrc = A + (size_t)arow * K + kstart + qa * 8;

  // B: wave q handles k-rows q*8..q*8+7; lane covers cols {lane, lane+64}
  const float* wsrc = W + (size_t)e * K * N + (size_t)(kstart + wave * 8) * N + n0 + lane;

  f32x4 acc[4][4] = {};
  const int wr = (wave >> 1) * 64;
  const int wc = (wave & 1) * 64;
  const int fr = lane & 15;
  const int fq = lane >> 4;

  // two named register slots (tile parity): slot s holds tile t with t&1==s
  short8 pA00, pA01, pA10, pA11;
  float pBa0[8], pBb0[8], pBa1[8], pBb1[8];

  // ---- prologue: load tile0 -> slot0, tile1 -> slot1; write slot0 -> buf0 ----
  pA00 = *(const short8*)(asrc);
  pA01 = *(const short8*)(asrc + 16);
#pragma unroll
  for (int j = 0; j < 8; ++j) {
    pBa0[j] = wsrc[(size_t)j * N];
    pBb0[j] = wsrc[(size_t)j * N + 64];
  }
  pA10 = *(const short8*)(asrc + 32);
  pA11 = *(const short8*)(asrc + 48);
  {
    const float* wp_ = wsrc + (size_t)32 * N;
#pragma unroll
    for (int j = 0; j < 8; ++j) {
      pBa1[j] = wp_[(size_t)j * N];
      pBb1[j] = wp_[(size_t)j * N + 64];
    }
  }
  *(short8*)&lA[0][qa * 1024 + ra * 8] = pA00;
  *(short8*)&lA[0][(qa + 2) * 1024 + ra * 8] = pA01;
  {
    short8 c0_, c1_;
#pragma unroll
    for (int j = 0; j < 8; ++j) {
      c0_[j] = (short)f2bf(pBa0[j]);
      c1_[j] = (short)f2bf(pBb0[j]);
    }
    *(short8*)&lB[0][wave * 1024 + lane * 8] = c0_;
    *(short8*)&lB[0][wave * 1024 + (lane + 64) * 8] = c1_;
  }
  asm volatile("s_waitcnt lgkmcnt(0)" ::: "memory");
  __builtin_amdgcn_s_barrier();
  asm volatile("" ::: "memory");

#define STEP_BODY(TV, CUR, NXT)                                                     \
  {                                                                                 \
    const int tv_ = (TV);                                                           \
    if (tv_ + 2 < NSTEP) { /* load tile tv+2 into slot CUR (raw, no cvt) */         \
      const unsigned short* ap_ = asrc + (tv_ + 2) * 32;                            \
      pA##CUR##0 = *(const short8*)ap_;                                             \
      pA##CUR##1 = *(const short8*)(ap_ + 16);                                      \
      const float* wp_ = wsrc + (size_t)(tv_ + 2) * 32 * N;                         \
      _Pragma("unroll") for (int j = 0; j < 8; ++j) {                               \
        pBa##CUR[j] = wp_[(size_t)j * N];                                           \
        pBb##CUR[j] = wp_[(size_t)j * N + 64];                                      \
      }                                                                             \
    }                                                                               \
    if (tv_ + 1 < NSTEP) { /* write slot NXT (tile tv+1, loaded last step) */       \
      *(short8*)&lA[NXT][qa * 1024 + ra * 8] = pA##NXT##0;                          \
      *(short8*)&lA[NXT][(qa + 2) * 1024 + ra * 8] = pA##NXT##1;                    \
      short8 c0_, c1_;                                                              \
      _Pragma("unroll") for (int j = 0; j < 8; ++j) {                               \
        c0_[j] = (short)f2bf(pBa##NXT[j]);                                          \
        c1_[j] = (short)f2bf(pBb##NXT[j]);                                          \
      }                                                                             \
      *(short8*)&lB[NXT][wave * 1024 + lane * 8] = c0_;                             \
      *(short8*)&lB[NXT][wave * 1024 + (lane + 64) * 8] = c1_;                      \
    }                                                                               \
    short8 af_[4], bf_[4];                                                          \
    _Pragma("unroll") for (int m = 0; m < 4; ++m)                                   \
        af_[m] = *(const short8*)&lA[CUR][fq * 1024 + (wr + m * 16 + fr) * 8];      \
    _Pragma("unroll") for (int n = 0; n < 4; ++n)                                   \
        bf_[n] = *(const short8*)&lB[CUR][fq * 1024 + (wc + n * 16 + fr) * 8];      \
    __builtin_amdgcn_s_setprio(1);                                                  \
    _Pragma("unroll") for (int m = 0; m < 4; ++m)                                   \
        _Pragma("unroll") for (int n = 0; n < 4; ++n)                               \
            acc[m][n] =                                                             \
                __builtin_amdgcn_mfma_f32_16x16x32_bf16(af_[m], bf_[n],             \
                                                        acc[m][n], 0, 0, 0);        \
    __builtin_amdgcn_s_setprio(0);                                                  \
    asm volatile("s_waitcnt lgkmcnt(0)" ::: "memory");                              \
    __builtin_amdgcn_s_barrier();                                                   \
    asm volatile("" ::: "memory");                                                  \
  }

  for (int t = 0; t < NSTEP; t += 2) {
    STEP_BODY(t, 0, 1);
    STEP_BODY(t + 1, 1, 0);
  }
#undef STEP_BODY

  if (MODE == 0) {
    unsigned short* Hout = (unsigned short*)outp;
    float bv[4];
#pragma unroll
    for (int n = 0; n < 4; ++n) bv[n] = bias[e * N + n0 + wc + n * 16 + fr];
#pragma unroll
    for (int m = 0; m < 4; ++m) {
#pragma unroll
      for (int j = 0; j < 4; ++j) {
        int rg = m0 + wr + m * 16 + fq * 4 + j;
        if (rg < cnt) {
          size_t base = (size_t)(hoff + rg) * N;
#pragma unroll
          for (int n = 0; n < 4; ++n) {
            float hv = acc[m][n][j] + bv[n];
            hv = fmaxf(hv, 0.f);
            Hout[base + n0 + wc + n * 16 + fr] = f2bf(hv);
          }
        }
      }
    }
  } else {
    float* Out = (float*)outp;
#pragma unroll
    for (int m = 0; m < 4; ++m) {
#pragma unroll
      for (int j = 0; j < 4; ++j) {
        int rg = m0 + wr + m * 16 + fq * 4 + j;
        if (rg < cnt) {
          int token = perm[e * CAP + rg];
          size_t base = ((size_t)(token & (S_ - 1)) * B_ + (token >> 11)) * (size_t)D_;
#pragma unroll
          for (int n = 0; n < 4; ++n)
            atomicAdd(&Out[base + n0 + wc + n * 16 + fr], acc[m][n][j]);
        }
      }
    }
  }
}

extern "C" void kernel_launch(void* const* d_in, const int* in_sizes, int n_in,
                              void* d_out, int out_size, void* d_ws, size_t ws_size,
                              hipStream_t stream) {
  const float* x    = (const float*)d_in[0];
  const float* cent = (const float*)d_in[1];
  const float* lng  = (const float*)d_in[2];
  const float* lnb  = (const float*)d_in[3];
  const float* W1   = (const float*)d_in[4];
  const float* b1   = (const float*)d_in[5];
  const float* W2   = (const float*)d_in[6];
  const float* b2   = (const float*)d_in[7];
  float* out = (float*)d_out;

  char* ws = (char*)d_ws;
  int* counts = (int*)(ws + 0);          // 8 ints
  int* offs   = (int*)(ws + 64);         // 9 ints
  int* tabF1  = (int*)(ws + 4096);       // NTABF ints (8KB)
  int* tabF2  = (int*)(ws + 12288);      // NTABF ints (8KB)
  int* perm   = (int*)(ws + 20480);      // [E][CAP] ints, 32KB
  unsigned short* Xb = (unsigned short*)(ws + ((size_t)1 << 18)); // [E][CAP][D] bf16, 16MB
  unsigned short* H  = (unsigned short*)(ws + ((size_t)1 << 25)); // [T][F] bf16 compact, 32MB

  if (ws_size < ((size_t)1 << 26)) return;  // need 64MB scratch

  hipMemsetAsync(counts, 0, 64, stream);
  gate_ln_kernel<<<T_ / 4, 256, 0, stream>>>(x, cent, lng, lnb, b2, counts, perm, Xb, out);
  prefix_kernel<<<1, 256, 0, stream>>>(counts, offs, tabF1, tabF2);
  // FF1: H = relu(Xb * W1 + b1)
  moe_gemm_kernel<D_, F_, 0, 1><<<NTABF, 256, 0, stream>>>(
      Xb, W1, b1, counts, offs, tabF1, perm, (void*)H);
  // FF2: out += H * W2 (split-K=4; out pre-initialized with x + b2)
  moe_gemm_kernel<F_, D_, 1, 4><<<NTABF, 256, 0, stream>>>(
      H, W2, nullptr, counts, offs, tabF2, perm, (void*)out);
}